// Round 6
// baseline (905.269 us; speedup 1.0000x reference)
//
#include <hip/hip_runtime.h>
#include <hip/hip_bf16.h>
#include <stddef.h>

// Problem constants
#define NB   65536   // batch
#define XC   130     // x row stride (IN+1+LAT)
#define LATD 128
#define HIDD 2048
#define JC   1024    // collapsed output cols (IN+1)*OUT
#define OC   512     // OUT
#define BM   128     // rows per main block
#define BN   512     // collapsed cols per main block
#define KCH  32      // K-chunk
#define NKC  64      // HIDD/KCH
#define BAND 16384   // rows per band (h staging)

typedef __bf16 bf16_t;
typedef bf16_t bf16x8 __attribute__((ext_vector_type(8)));
typedef float  f32x4  __attribute__((ext_vector_type(4)));

typedef __attribute__((address_space(1))) const unsigned char ga_u8;
typedef __attribute__((address_space(3))) unsigned char ls_u8;

__device__ __forceinline__ void dma16(const void* g, void* l) {
  __builtin_amdgcn_global_load_lds((ga_u8*)g, (ls_u8*)l, 16, 0, 0);
}

// ---------- prep 1: fc1wT[n][k] = bf16(fc1_w[k][n])
__global__ void prep_fc1(const float* __restrict__ fc1w, bf16_t* __restrict__ fc1wT) {
  int t = blockIdx.x * blockDim.x + threadIdx.x;
  int k = t & (LATD - 1);
  int n = t >> 7;
  fc1wT[(size_t)n * LATD + k] = (bf16_t)fc1w[(size_t)k * HIDD + n];
}

// ---------- prep 2: collapse fc2 against v, permute cols, transpose.
// collapsed c -> g=c>>5, half=(c>>4)&1, col16=c&15; out-col o=g*16+col16; jj=o+half*512.
__global__ void prep_fc2(const float* __restrict__ x, const float* __restrict__ fc2w,
                         const float* __restrict__ fc2b, const float* __restrict__ dil,
                         const float* __restrict__ shp, bf16_t* __restrict__ w2pT,
                         float* __restrict__ b2p) {
  int t = blockIdx.x * blockDim.x + threadIdx.x;
  int k = t & (HIDD - 1);
  int c = t >> 11;
  float s  = x[(size_t)(NB - 1) * XC + 1];
  float t0 = s * dil[0] + shp[0];
  float t1 = s * dil[1] + shp[1];
  float t2 = s * dil[2] + shp[2];
  float t3 = s * dil[3] + shp[3];
  float v0 = cosf(t0) + cosf(t2);
  float v1 = sinf(t1) + sinf(t3);
  int jj = ((c >> 5) * 16 + (c & 15)) + (((c >> 4) & 1) << 9);
  float w0 = fc2w[(size_t)k * 2048 + 2 * jj];
  float w1 = fc2w[(size_t)k * 2048 + 2 * jj + 1];
  w2pT[(size_t)c * HIDD + k] = (bf16_t)(w0 * v0 + w1 * v1);
  if (k == 0) b2p[c] = fc2b[2 * jj] * v0 + fc2b[2 * jj + 1] * v1;
}

// ---------- h kernel: one band of h = tanh(z @ fc1_w + b), row-major [BAND][HIDD] bf16.
// 256 threads = 4 waves; block = 64 rows; fc1wT read direct from L2 (512KB resident).
__global__ __launch_bounds__(256) void h_kernel(
    const float* __restrict__ x, const float* __restrict__ fc1b,
    const bf16_t* __restrict__ fc1wT, bf16_t* __restrict__ h, int band)
{
  __shared__ bf16_t tile[4][16 * 64];   // per-wave 2KB transpose buffer, XOR-swizzled
  const int t   = threadIdx.x;
  const int w   = t >> 6;
  const int l   = t & 63;
  const int lhi = l >> 4;
  const int llo = l & 15;
  const size_t b0 = (size_t)band * BAND + (size_t)blockIdx.x * 64;
  const int    hr0 = blockIdx.x * 64 + w * 16;      // band-local h row base

  // z rows w*16+llo, K=128, in registers (verified pattern)
  bf16x8 za[4];
  {
    const float* zsrc = x + (b0 + w * 16 + llo) * XC + 2;
#pragma unroll
    for (int ks = 0; ks < 4; ++ks) {
      bf16x8 pk;
#pragma unroll
      for (int i = 0; i < 4; ++i) {
        float2 f = *(const float2*)(zsrc + ks * 32 + lhi * 8 + 2 * i);
        pk[2 * i]     = (bf16_t)f.x;
        pk[2 * i + 1] = (bf16_t)f.y;
      }
      za[ks] = pk;
    }
  }

  for (int j = 0; j < 32; ++j) {        // 64 hid cols per iter
#pragma unroll
    for (int nt = 0; nt < 4; ++nt) {
      int col = j * 64 + nt * 16 + llo;
      f32x4 c1 = {};
#pragma unroll
      for (int ks = 0; ks < 4; ++ks) {
        bf16x8 b = *(const bf16x8*)(fc1wT + (size_t)col * LATD + ks * 32 + lhi * 8);
        c1 = __builtin_amdgcn_mfma_f32_16x16x32_bf16(za[ks], b, c1, 0, 0, 0);
      }
      float bias = fc1b[col];
#pragma unroll
      for (int r = 0; r < 4; ++r) {
        float pre = c1[r] + bias;
        float e   = __builtin_amdgcn_exp2f(pre * 2.88539008177792681f);  // e^(2x)
        float th  = 1.0f - 2.0f * __builtin_amdgcn_rcpf(e + 1.0f);
        int row = lhi * 4 + r;
        int tb  = row * 128 + (((nt * 16 + llo) * 2) ^ ((row & 7) << 4));
        *(bf16_t*)((char*)tile[w] + tb) = (bf16_t)th;
      }
    }
    // transpose-readback (wave-private, lgkmcnt auto) + coalesced 16B stores
#pragma unroll
    for (int half = 0; half < 2; ++half) {
      int row = l >> 2;
      int rb  = row * 128 + ((((l & 3) * 16) + half * 64) ^ ((row & 7) << 4));
      bf16x8 v = *(const bf16x8*)((const char*)tile[w] + rb);
      *(bf16x8*)(h + (size_t)(hr0 + row) * HIDD + j * 64 + (l & 3) * 8 + half * 32) = v;
    }
  }
}

// ---------- main kernel: pure GEMM  acc += h_band @ w2pT over K=2048, + epilogue.
// 512 threads = 8 waves; block = 128 rows x 512 cols; wave tile 64x128 ((2,4) split).
// Per chunk: {DMA w2t(kc+1) 4/wave + ht(kc+1) 1/wave; G2(kc): 12 ds_read + 32 MFMA; bar}
// LDS layouts are k-slot-planar: byte(idx, ks) = ks*PLANE + idx*16 -> DMA dest is
// uniform+lane*16 AND reads are 2-way-max bank aliasing (conflict-free).
__global__ __launch_bounds__(512, 2) void wag_main(
    const float* __restrict__ x, const bf16_t* __restrict__ hband,
    const bf16_t* __restrict__ w2pT, const float* __restrict__ b2p,
    float* __restrict__ out, int band)
{
  __shared__ bf16_t w2t[2][BN * KCH];   // 2x32KB, planar: ks*8192 + col*16 bytes
  __shared__ bf16_t ht[2][BM * KCH];    // 2x8KB,  planar: ks*2048 + row*16 bytes
  __shared__ float  inp_lds[BM];

  const int t   = threadIdx.x;
  const int w   = t >> 6;
  const int l   = t & 63;
  const int lhi = l >> 4;
  const int llo = l & 15;
  const size_t b0 = (size_t)band * BAND + (size_t)blockIdx.x * BM;   // global row
  const int    hrow0 = blockIdx.x * BM;                              // band-local row
  const int    bc  = blockIdx.y * BN;
  const int    mrb = (w & 1) * 64;
  const int    ncb = (w >> 1) * 128;

  if (t < BM) inp_lds[t] = x[(b0 + t) * XC];

  f32x4 acc[4][8] = {};

  auto stage = [&](int kc) {
    const int buf = kc & 1;
    // w2t: 32 segs of 1KB; seg j: ks=j>>3, cb=j&7; lane col=cb*64+l
#pragma unroll
    for (int q = 0; q < 4; ++q) {
      int j  = w * 4 + q;
      int ks = j >> 3, cb = j & 7;
      const char* src = (const char*)w2pT +
          ((size_t)(bc + cb * 64 + l) * HIDD + kc * KCH + ks * 8) * 2;
      dma16(src, (char*)w2t[buf] + ks * 8192 + cb * 1024 + l * 16);
    }
    // ht: 8 segs; seg w: ks=w>>1, rb=w&1; lane row=rb*64+l
    {
      int ks = w >> 1, rb = w & 1;
      const char* src = (const char*)hband +
          ((size_t)(hrow0 + rb * 64 + l) * HIDD + kc * KCH + ks * 8) * 2;
      dma16(src, (char*)ht[buf] + ks * 2048 + rb * 1024 + l * 16);
    }
  };

  auto G2 = [&](int kc) {
    const int buf = kc & 1;
    bf16x8 a[4];
#pragma unroll
    for (int mt = 0; mt < 4; ++mt)
      a[mt] = *(const bf16x8*)((const char*)ht[buf] +
               (lhi * 2048 + (mrb + mt * 16 + llo) * 16));
    __builtin_amdgcn_s_setprio(1);
#pragma unroll
    for (int nt = 0; nt < 8; ++nt) {
      bf16x8 b = *(const bf16x8*)((const char*)w2t[buf] +
                 (lhi * 8192 + (ncb + nt * 16 + llo) * 16));
#pragma unroll
      for (int mt = 0; mt < 4; ++mt)
        acc[mt][nt] = __builtin_amdgcn_mfma_f32_16x16x32_bf16(a[mt], b, acc[mt][nt], 0, 0, 0);
    }
    __builtin_amdgcn_s_setprio(0);
  };

  stage(0);
  __syncthreads();                       // buffers 0 ready (vmcnt drained)
  for (int kc = 0; kc < NKC; ++kc) {
    if (kc < NKC - 1) stage(kc + 1);     // issue first: full interval in flight
    G2(kc);
    if (kc < NKC - 1) __syncthreads();   // drains DMA; WAR-safe (see analysis)
  }

  // epilogue: weight (nt even) / bias (nt odd) in SAME lane; 64B-contig stores
#pragma unroll
  for (int p = 0; p < 4; ++p) {
    int cw = bc + ncb + p * 32 + llo;
    float bw = b2p[cw];
    float bb = b2p[cw + 16];
    int oc = (bc + ncb + p * 32) / 2 + llo;
#pragma unroll
    for (int mt = 0; mt < 4; ++mt) {
#pragma unroll
      for (int r = 0; r < 4; ++r) {
        int row = mrb + mt * 16 + lhi * 4 + r;
        float wv = acc[mt][2 * p][r] + bw;
        float bv = acc[mt][2 * p + 1][r] + bb;
        out[(b0 + row) * OC + oc] = inp_lds[row] * wv + bv;
      }
    }
  }
}

extern "C" void kernel_launch(void* const* d_in, const int* in_sizes, int n_in,
                              void* d_out, int out_size, void* d_ws, size_t ws_size,
                              hipStream_t stream) {
  const float* x    = (const float*)d_in[0];
  const float* fc1w = (const float*)d_in[1];
  const float* fc1b = (const float*)d_in[2];
  const float* fc2w = (const float*)d_in[3];
  const float* fc2b = (const float*)d_in[4];
  const float* dil  = (const float*)d_in[5];
  const float* shp  = (const float*)d_in[6];
  float* out = (float*)d_out;

  // ws: fc1wT 512KB | w2pT 4MB | b2p 4KB | pad | hband 64MB  => ~72MB
  bf16_t* fc1wT = (bf16_t*)d_ws;
  bf16_t* w2pT  = fc1wT + (size_t)HIDD * LATD;
  float*  b2p   = (float*)(w2pT + (size_t)JC * HIDD);
  bf16_t* hband = (bf16_t*)((char*)d_ws + ((512 * 1024) + (4 * 1024 * 1024) + 65536));

  prep_fc1<<<(HIDD * LATD) / 256, 256, 0, stream>>>(fc1w, fc1wT);
  prep_fc2<<<(JC * HIDD) / 256, 256, 0, stream>>>(x, fc2w, fc2b, dil, shp, w2pT, b2p);

  for (int band = 0; band < NB / BAND; ++band) {
    h_kernel<<<BAND / 64, 256, 0, stream>>>(x, fc1b, fc1wT, hband, band);
    wag_main<<<dim3(BAND / BM, JC / BN), 512, 0, stream>>>(x, hband, w2pT, b2p, out, band);
  }
}

// Round 8
// 696.276 us; speedup vs baseline: 1.3002x; 1.3002x over previous
//
#include <hip/hip_runtime.h>
#include <hip/hip_bf16.h>
#include <stddef.h>

// Problem constants
#define NB   65536   // batch
#define XC   130     // x row stride (IN+1+LAT)
#define LATD 128
#define HIDD 2048
#define JC   1024    // collapsed output cols (IN+1)*OUT
#define OC   512     // OUT
#define BM   128     // rows per block
#define BN   512     // collapsed cols per block
#define KCH  32      // K-chunk (hid cols per step)
#define NKC  64      // HIDD/KCH

typedef __bf16 bf16_t;
typedef bf16_t bf16x4 __attribute__((ext_vector_type(4)));
typedef bf16_t bf16x8 __attribute__((ext_vector_type(8)));
typedef float  f32x4  __attribute__((ext_vector_type(4)));

typedef __attribute__((address_space(1))) const unsigned char ga_u8;
typedef __attribute__((address_space(3))) unsigned char ls_u8;

__device__ __forceinline__ void dma16(const void* g, void* l) {
  __builtin_amdgcn_global_load_lds((ga_u8*)g, (ls_u8*)l, 16, 0, 0);
}

// ---------- prep 1: fc1wT[n][k] = bf16(fc1_w[k][n])
__global__ void prep_fc1(const float* __restrict__ fc1w, bf16_t* __restrict__ fc1wT) {
  int t = blockIdx.x * blockDim.x + threadIdx.x;
  int k = t & (LATD - 1);
  int n = t >> 7;
  fc1wT[(size_t)n * LATD + k] = (bf16_t)fc1w[(size_t)k * HIDD + n];
}

// ---------- prep 2: collapse fc2 against v, permute cols, transpose.
// collapsed c -> g=c>>5, half=(c>>4)&1, col16=c&15; out-col o=g*16+col16; jj=o+half*512.
__global__ void prep_fc2(const float* __restrict__ x, const float* __restrict__ fc2w,
                         const float* __restrict__ fc2b, const float* __restrict__ dil,
                         const float* __restrict__ shp, bf16_t* __restrict__ w2pT,
                         float* __restrict__ b2p) {
  int t = blockIdx.x * blockDim.x + threadIdx.x;
  int k = t & (HIDD - 1);
  int c = t >> 11;
  float s  = x[(size_t)(NB - 1) * XC + 1];
  float t0 = s * dil[0] + shp[0];
  float t1 = s * dil[1] + shp[1];
  float t2 = s * dil[2] + shp[2];
  float t3 = s * dil[3] + shp[3];
  float v0 = cosf(t0) + cosf(t2);
  float v1 = sinf(t1) + sinf(t3);
  int jj = ((c >> 5) * 16 + (c & 15)) + (((c >> 4) & 1) << 9);
  float w0 = fc2w[(size_t)k * 2048 + 2 * jj];
  float w1 = fc2w[(size_t)k * 2048 + 2 * jj + 1];
  w2pT[(size_t)c * HIDD + k] = (bf16_t)(w0 * v0 + w1 * v1);
  if (k == 0) b2p[c] = fc2b[2 * jj] * v0 + fc2b[2 * jj + 1] * v1;
}

// ---------- main fused kernel: 512 threads = 8 waves, BM=128 x BN=512, KCH=32.
// Counted-vmcnt pipeline (T4): raw s_barrier, never vmcnt(0) in the loop.
// Per sub-chunk: {stage_w2(kc+2) 4xDMA + loadA(kc+2) 4xglobal (8 VM ops);
//   G1(kc+1) swapped-MFMA -> packed ds_write ht[(kc+1)&1]; G2(kc);
//   s_waitcnt vmcnt(8) lgkmcnt(0); s_barrier}
// vmcnt(8) = this sub-iter's 8 VM ops outstanding => previous sub-iter's staging
// complete; current staging stays in flight across the barrier.
__global__ __launch_bounds__(512, 2) void wag_main(
    const float* __restrict__ x, const float* __restrict__ fc1b,
    const bf16_t* __restrict__ fc1wT, const bf16_t* __restrict__ w2pT,
    const float* __restrict__ b2p, float* __restrict__ out)
{
  __shared__ bf16_t w2t[3][BN * KCH];   // 3x32KB, planar: ks*8192 + col*16 bytes
  __shared__ bf16_t ht[2][BM * KCH];    // 2x8KB,  planar: ks*2048 + row*16 bytes
  __shared__ float  fb_lds[HIDD];       // 8KB fc1 bias
  __shared__ float  inp_lds[BM];

  const int t   = threadIdx.x;
  const int w   = t >> 6;
  const int l   = t & 63;
  const int lhi = l >> 4;
  const int llo = l & 15;
  const size_t b0 = (size_t)blockIdx.x * BM;
  const int    bc  = blockIdx.y * BN;
  const int    hb  = w & 1;            // G1 hid-16 half
  const int    gb  = (w >> 1) * 32;    // G1 batch-32 group base
  const int    mrb = (w & 1) * 64;     // G2 row base
  const int    ncb = (w >> 1) * 128;   // G2 col base

  // ---- prologue: fc1b -> LDS, inp, za regs (z rows gb+bb2*16+llo, K=128)
  ((float4*)fb_lds)[t] = ((const float4*)fc1b)[t];          // 512 x 16B = 8KB
  if (t < BM) inp_lds[t] = x[(b0 + t) * XC];

  bf16x8 za[2][4];
#pragma unroll
  for (int bb2 = 0; bb2 < 2; ++bb2) {
    const float* zsrc = x + (b0 + gb + bb2 * 16 + llo) * XC + 2;
#pragma unroll
    for (int ks = 0; ks < 4; ++ks) {
      bf16x8 pk;
#pragma unroll
      for (int i = 0; i < 4; ++i) {
        float2 f = *(const float2*)(zsrc + ks * 32 + lhi * 8 + 2 * i);
        pk[2 * i]     = (bf16_t)f.x;
        pk[2 * i + 1] = (bf16_t)f.y;
      }
      za[bb2][ks] = pk;
    }
  }

  f32x4 acc[4][8] = {};

  auto stage_w2 = [&](int kc) {        // 32KB into w2t[kc%3], 4 dma16/wave
    const int buf = kc % 3;
#pragma unroll
    for (int q = 0; q < 4; ++q) {
      int j  = w * 4 + q;
      int ks = j >> 3, cb = j & 7;
      const char* src = (const char*)w2pT +
          ((size_t)(bc + cb * 64 + l) * HIDD + kc * KCH + ks * 8) * 2;
      dma16(src, (char*)w2t[buf] + ks * 8192 + cb * 1024 + l * 16);
    }
  };

  auto loadA = [&](bf16x8 (&A)[4], int j) {  // fc1 A-frag (hid rows), 4 x 16B from L2
    const bf16_t* base = fc1wT + (size_t)(j * KCH + hb * 16 + llo) * LATD + lhi * 8;
#pragma unroll
    for (int ks = 0; ks < 4; ++ks) A[ks] = *(const bf16x8*)(base + ks * 32);
  };

  // G1 swapped: D[hid][batch] = fc1_frag x za; lane holds 4 consecutive k -> b64 write
  auto G1 = [&](int j, bf16x8 (&A)[4]) {
    float4 fb = *(const float4*)(&fb_lds[j * KCH + hb * 16 + lhi * 4]);
#pragma unroll
    for (int bb2 = 0; bb2 < 2; ++bb2) {
      f32x4 c1 = {};
#pragma unroll
      for (int ks = 0; ks < 4; ++ks)
        c1 = __builtin_amdgcn_mfma_f32_16x16x32_bf16(A[ks], za[bb2][ks], c1, 0, 0, 0);
      bf16x4 pk;
#pragma unroll
      for (int r = 0; r < 4; ++r) {
        float pre = c1[r] + ((const float*)&fb)[r];
        float e   = __builtin_amdgcn_exp2f(pre * 2.88539008177792681f);  // e^(2x)
        float th  = 1.0f - 2.0f * __builtin_amdgcn_rcpf(e + 1.0f);
        pk[r] = (bf16_t)th;
      }
      int row = gb + bb2 * 16 + llo;
      int off = (hb * 2 + (lhi >> 1)) * 2048 + row * 16 + (lhi & 1) * 8;
      *(bf16x4*)((char*)ht[j & 1] + off) = pk;
    }
  };

  auto G2 = [&](int kc) {
    const char* hbuf = (const char*)ht[kc & 1];
    const char* wbuf = (const char*)w2t[kc % 3];
    bf16x8 a[4];
#pragma unroll
    for (int mt = 0; mt < 4; ++mt)
      a[mt] = *(const bf16x8*)(hbuf + lhi * 2048 + (mrb + mt * 16 + llo) * 16);
    __builtin_amdgcn_s_setprio(1);
#pragma unroll
    for (int nt = 0; nt < 8; ++nt) {
      bf16x8 b = *(const bf16x8*)(wbuf + lhi * 8192 + (ncb + nt * 16 + llo) * 16);
#pragma unroll
      for (int mt = 0; mt < 4; ++mt)
        acc[mt][nt] = __builtin_amdgcn_mfma_f32_16x16x32_bf16(a[mt], b, acc[mt][nt], 0, 0, 0);
    }
    __builtin_amdgcn_s_setprio(0);
  };

  bf16x8 A0[4], A1[4];
  stage_w2(0);
  stage_w2(1);
  loadA(A0, 0);
  loadA(A1, 1);
  __syncthreads();                 // full drain once: w2t[0],w2t[1],fb_lds ready
  G1(0, A0);
  __syncthreads();                 // ht[0] visible

  // steady state: 31 iterations, 2 chunks each. Every sub-iter issues exactly
  // 8 VM ops (4 dma16 + 4 loadA) -> vmcnt(8) == "previous sub-iter complete".
  for (int kc = 0; kc < 62; kc += 2) {
    // sub A
    stage_w2(kc + 2);
    loadA(A0, kc + 2);
    G1(kc + 1, A1);
    G2(kc);
    asm volatile("s_waitcnt vmcnt(8) lgkmcnt(0)" ::: "memory");
    __builtin_amdgcn_s_barrier();
    // sub B  (stage/loadA now UNCONDITIONAL — round-7 bug: chunk 63 was skipped)
    stage_w2(kc + 3);
    loadA(A1, kc + 3);
    G1(kc + 2, A0);
    G2(kc + 1);
    asm volatile("s_waitcnt vmcnt(8) lgkmcnt(0)" ::: "memory");
    __builtin_amdgcn_s_barrier();
  }
  // tail: chunks 62,63 (full drain, outside hot loop)
  G1(63, A1);
  G2(62);
  asm volatile("s_waitcnt vmcnt(0) lgkmcnt(0)" ::: "memory");
  __builtin_amdgcn_s_barrier();
  G2(63);

  // ---- epilogue: weight (nt even) / bias (nt odd) in SAME lane; 64B-contig stores
#pragma unroll
  for (int p = 0; p < 4; ++p) {
    int cw = bc + ncb + p * 32 + llo;
    float bw = b2p[cw];
    float bb = b2p[cw + 16];
    int oc = (bc + ncb + p * 32) / 2 + llo;
#pragma unroll
    for (int mt = 0; mt < 4; ++mt) {
#pragma unroll
      for (int r = 0; r < 4; ++r) {
        int row = mrb + mt * 16 + lhi * 4 + r;
        float wv = acc[mt][2 * p][r] + bw;
        float bv = acc[mt][2 * p + 1][r] + bb;
        out[(b0 + row) * OC + oc] = inp_lds[row] * wv + bv;
      }
    }
  }
}

extern "C" void kernel_launch(void* const* d_in, const int* in_sizes, int n_in,
                              void* d_out, int out_size, void* d_ws, size_t ws_size,
                              hipStream_t stream) {
  const float* x    = (const float*)d_in[0];
  const float* fc1w = (const float*)d_in[1];
  const float* fc1b = (const float*)d_in[2];
  const float* fc2w = (const float*)d_in[3];
  const float* fc2b = (const float*)d_in[4];
  const float* dil  = (const float*)d_in[5];
  const float* shp  = (const float*)d_in[6];
  float* out = (float*)d_out;

  // ws layout: fc1wT (512KB bf16) | w2pT (4MB bf16) | b2p (4KB f32)
  bf16_t* fc1wT = (bf16_t*)d_ws;
  bf16_t* w2pT  = fc1wT + (size_t)HIDD * LATD;
  float*  b2p   = (float*)(w2pT + (size_t)JC * HIDD);

  prep_fc1<<<(HIDD * LATD) / 256, 256, 0, stream>>>(fc1w, fc1wT);
  prep_fc2<<<(JC * HIDD) / 256, 256, 0, stream>>>(x, fc2w, fc2b, dil, shp, w2pT, b2p);
  wag_main<<<dim3(NB / BM, JC / BN), 512, 0, stream>>>(x, fc1b, fc1wT, w2pT, b2p, out);
}

// Round 9
// 540.940 us; speedup vs baseline: 1.6735x; 1.2872x over previous
//
#include <hip/hip_runtime.h>
#include <hip/hip_bf16.h>
#include <stddef.h>

// Problem constants
#define NB   65536   // batch
#define XC   130     // x row stride (IN+1+LAT)
#define LATD 128
#define HIDD 2048
#define JC   1024    // collapsed output cols (IN+1)*OUT
#define OC   512     // OUT
#define BAND 16384   // rows per band (h staging, 64MB -> L3-resident)
#define HBLK 32      // h_kernel rows per block
#define WBM  256     // wag tile rows
#define WBN  256     // wag tile collapsed cols
#define BK   64      // wag K-tile
#define NKT  32      // HIDD/BK

typedef __bf16 bf16_t;
typedef bf16_t bf16x8 __attribute__((ext_vector_type(8)));
typedef float  f32x4  __attribute__((ext_vector_type(4)));

typedef __attribute__((address_space(1))) const unsigned char ga_u8;
typedef __attribute__((address_space(3))) unsigned char ls_u8;

__device__ __forceinline__ void dma16(const void* g, void* l) {
  __builtin_amdgcn_global_load_lds((ga_u8*)g, (ls_u8*)l, 16, 0, 0);
}

// ---------- prep 1: fc1wT[n][k] = bf16(fc1_w[k][n])
__global__ void prep_fc1(const float* __restrict__ fc1w, bf16_t* __restrict__ fc1wT) {
  int t = blockIdx.x * blockDim.x + threadIdx.x;
  int k = t & (LATD - 1);
  int n = t >> 7;
  fc1wT[(size_t)n * LATD + k] = (bf16_t)fc1w[(size_t)k * HIDD + n];
}

// ---------- prep 2: collapse fc2 against v, permute cols, transpose.
// collapsed c -> g=c>>5, half=(c>>4)&1, col16=c&15; out-col o=g*16+col16; jj=o+half*512.
__global__ void prep_fc2(const float* __restrict__ x, const float* __restrict__ fc2w,
                         const float* __restrict__ fc2b, const float* __restrict__ dil,
                         const float* __restrict__ shp, bf16_t* __restrict__ w2pT,
                         float* __restrict__ b2p) {
  int t = blockIdx.x * blockDim.x + threadIdx.x;
  int k = t & (HIDD - 1);
  int c = t >> 11;
  float s  = x[(size_t)(NB - 1) * XC + 1];
  float t0 = s * dil[0] + shp[0];
  float t1 = s * dil[1] + shp[1];
  float t2 = s * dil[2] + shp[2];
  float t3 = s * dil[3] + shp[3];
  float v0 = cosf(t0) + cosf(t2);
  float v1 = sinf(t1) + sinf(t3);
  int jj = ((c >> 5) * 16 + (c & 15)) + (((c >> 4) & 1) << 9);
  float w0 = fc2w[(size_t)k * 2048 + 2 * jj];
  float w1 = fc2w[(size_t)k * 2048 + 2 * jj + 1];
  w2pT[(size_t)c * HIDD + k] = (bf16_t)(w0 * v0 + w1 * v1);
  if (k == 0) b2p[c] = fc2b[2 * jj] * v0 + fc2b[2 * jj + 1] * v1;
}

// ---------- h kernel: h[row][k] = tanh(z @ fc1_w + b) for one band, row-major bf16.
// 512 thr = 8 waves; block = 32 rows; wave w: rows (w&1)*16..+16, hid quarter (w>>1)*512.
// Grid 512 blocks -> 2 blocks/CU, 4 waves/SIMD: TLP hides L2 latency.
__global__ __launch_bounds__(512, 4) void h_kernel(
    const float* __restrict__ x, const float* __restrict__ fc1b,
    const bf16_t* __restrict__ fc1wT, bf16_t* __restrict__ h, int band)
{
  __shared__ bf16_t tile[8][16 * 64];   // per-wave 2KB transpose buffer, XOR-swizzled
  const int t   = threadIdx.x;
  const int w   = t >> 6;
  const int l   = t & 63;
  const int lhi = l >> 4;
  const int llo = l & 15;
  const size_t b0 = (size_t)band * BAND + (size_t)blockIdx.x * HBLK;
  const int r0   = (w & 1) * 16;
  const int H0   = (w >> 1) * 512;
  const int hr0d = blockIdx.x * HBLK + r0;          // band-local store row base

  bf16x8 za[4];
  {
    const float* zsrc = x + (b0 + r0 + llo) * XC + 2;
#pragma unroll
    for (int ks = 0; ks < 4; ++ks) {
      bf16x8 pk;
#pragma unroll
      for (int i = 0; i < 4; ++i) {
        float2 f = *(const float2*)(zsrc + ks * 32 + lhi * 8 + 2 * i);
        pk[2 * i]     = (bf16_t)f.x;
        pk[2 * i + 1] = (bf16_t)f.y;
      }
      za[ks] = pk;
    }
  }

  for (int jj = 0; jj < 8; ++jj) {      // 64 hid cols per iter
    int c0 = H0 + jj * 64;
#pragma unroll
    for (int nt = 0; nt < 4; ++nt) {
      int col = c0 + nt * 16 + llo;
      f32x4 c1 = {};
#pragma unroll
      for (int ks = 0; ks < 4; ++ks) {
        bf16x8 b = *(const bf16x8*)(fc1wT + (size_t)col * LATD + ks * 32 + lhi * 8);
        c1 = __builtin_amdgcn_mfma_f32_16x16x32_bf16(za[ks], b, c1, 0, 0, 0);
      }
      float bias = fc1b[col];
#pragma unroll
      for (int r = 0; r < 4; ++r) {
        float pre = c1[r] + bias;
        float e   = __builtin_amdgcn_exp2f(pre * 2.88539008177792681f);  // e^(2x)
        float th  = 1.0f - 2.0f * __builtin_amdgcn_rcpf(e + 1.0f);
        int row = lhi * 4 + r;
        int tb  = row * 128 + (((nt * 16 + llo) * 2) ^ ((row & 7) << 4));
        *(bf16_t*)((char*)tile[w] + tb) = (bf16_t)th;
      }
    }
    // transpose readback (wave-private) + coalesced stores
#pragma unroll
    for (int half = 0; half < 2; ++half) {
      int row = l >> 2;
      int rb  = row * 128 + ((((l & 3) * 16) + half * 64) ^ ((row & 7) << 4));
      bf16x8 v = *(const bf16x8*)((const char*)tile[w] + rb);
      *(bf16x8*)(h + (size_t)(hr0d + row) * HIDD + c0 + (l & 3) * 8 + half * 32) = v;
    }
  }
}

// ---------- wag_main: pure 256x256-tile GEMM  acc += h_band @ w2pT^T, K=2048.
// 512 thr = 8 waves (2Mx4N -> 128x64 wave tiles). Full-tile dbuf (128KB LDS).
// Per K-tile: {stage(t+1) 8 gload_lds; vmcnt(8); bar#1; 2x{4 b-reads; 2x{4 a-reads;
//   16 MFMA}}; lgkm(0); bar#2}. Counted vmcnt: stage has a full iter in flight.
// LDS: [r][64k] 128B rows, XOR-swizzled via pre-swizzled DMA source (within-line).
__global__ __launch_bounds__(512, 2) void wag_main(
    const float* __restrict__ x, const bf16_t* __restrict__ hband,
    const bf16_t* __restrict__ w2pT, const float* __restrict__ b2p,
    float* __restrict__ out, int band)
{
  __shared__ bf16_t Ab[2][WBM * BK];    // 2x32KB
  __shared__ bf16_t Bb[2][WBN * BK];    // 2x32KB
  __shared__ float  inp_lds[WBM];

  const int t   = threadIdx.x;
  const int w   = t >> 6;
  const int l   = t & 63;
  const int lhi = l >> 4;
  const int llo = l & 15;
  const int hr0 = blockIdx.x * WBM;                 // band-local row base
  const size_t bg0 = (size_t)band * BAND + hr0;     // global row base
  const int bc  = blockIdx.y * WBN;
  const int mrb = (w >> 2) * 128;
  const int ncb = (w & 3) * 64;

  if (t < WBM) inp_lds[t] = x[(bg0 + t) * XC];

  f32x4 acc[8][4] = {};

  auto stageA = [&](int kt) {
    bf16_t* dst = Ab[kt & 1];
#pragma unroll
    for (int q = 0; q < 4; ++q) {
      int idx  = q * 512 + t;
      int row  = idx >> 3, slot = idx & 7;
      const char* src = (const char*)(hband + (size_t)(hr0 + row) * HIDD + kt * BK
                                      + ((slot ^ (row & 7)) * 8));
      dma16(src, (char*)dst + idx * 16);
    }
  };
  auto stageB = [&](int kt) {
    bf16_t* dst = Bb[kt & 1];
#pragma unroll
    for (int q = 0; q < 4; ++q) {
      int idx  = q * 512 + t;
      int col  = idx >> 3, slot = idx & 7;
      const char* src = (const char*)(w2pT + (size_t)(bc + col) * HIDD + kt * BK
                                      + ((slot ^ (col & 7)) * 8));
      dma16(src, (char*)dst + idx * 16);
    }
  };

  auto KSTEP = [&](int kt) {
    const char* Ab_ = (const char*)Ab[kt & 1];
    const char* Bb_ = (const char*)Bb[kt & 1];
#pragma unroll
    for (int ks2 = 0; ks2 < 2; ++ks2) {
      bf16x8 b[4];
#pragma unroll
      for (int j = 0; j < 4; ++j) {
        int col = ncb + j * 16 + llo;
        b[j] = *(const bf16x8*)(Bb_ + col * 128 + ((ks2 * 64 + lhi * 16) ^ ((col & 7) << 4)));
      }
#pragma unroll
      for (int rh = 0; rh < 2; ++rh) {
        bf16x8 a[4];
#pragma unroll
        for (int i = 0; i < 4; ++i) {
          int row = mrb + rh * 64 + i * 16 + llo;
          a[i] = *(const bf16x8*)(Ab_ + row * 128 + ((ks2 * 64 + lhi * 16) ^ ((row & 7) << 4)));
        }
        __builtin_amdgcn_s_setprio(1);
#pragma unroll
        for (int j = 0; j < 4; ++j)
#pragma unroll
          for (int i = 0; i < 4; ++i)
            acc[rh * 4 + i][j] =
                __builtin_amdgcn_mfma_f32_16x16x32_bf16(a[i], b[j], acc[rh * 4 + i][j], 0, 0, 0);
        __builtin_amdgcn_s_setprio(0);
      }
    }
  };

  stageA(0); stageB(0);
  __syncthreads();                       // prologue full drain: tile 0 ready
  for (int kt = 0; kt < NKT - 1; ++kt) {
    stageA(kt + 1); stageB(kt + 1);      // 8 VM ops -> buf^1, in flight across bars
    asm volatile("s_waitcnt vmcnt(8)" ::: "memory");   // S(kt) complete (counted)
    __builtin_amdgcn_s_barrier();        // bar#1: RAW — tile kt visible to all
    KSTEP(kt);
    asm volatile("s_waitcnt lgkmcnt(0)" ::: "memory");
    __builtin_amdgcn_s_barrier();        // bar#2: WAR — reads done before next stage
  }
  asm volatile("s_waitcnt vmcnt(0)" ::: "memory");     // tail drain (once)
  __builtin_amdgcn_s_barrier();
  KSTEP(NKT - 1);

  // ---- epilogue: weight (frag 2p) / bias (frag 2p+1) in SAME lane; 64B stores
#pragma unroll
  for (int p = 0; p < 2; ++p) {
    int cw = bc + ncb + p * 32 + llo;
    float bw = b2p[cw];
    float bb = b2p[cw + 16];
    int oc = (bc + ncb + p * 32) / 2 + llo;
#pragma unroll
    for (int fi = 0; fi < 8; ++fi) {
#pragma unroll
      for (int r = 0; r < 4; ++r) {
        int row = mrb + fi * 16 + lhi * 4 + r;
        float wv = acc[fi][2 * p][r] + bw;
        float bv = acc[fi][2 * p + 1][r] + bb;
        out[(bg0 + row) * OC + oc] = inp_lds[row] * wv + bv;
      }
    }
  }
}

extern "C" void kernel_launch(void* const* d_in, const int* in_sizes, int n_in,
                              void* d_out, int out_size, void* d_ws, size_t ws_size,
                              hipStream_t stream) {
  const float* x    = (const float*)d_in[0];
  const float* fc1w = (const float*)d_in[1];
  const float* fc1b = (const float*)d_in[2];
  const float* fc2w = (const float*)d_in[3];
  const float* fc2b = (const float*)d_in[4];
  const float* dil  = (const float*)d_in[5];
  const float* shp  = (const float*)d_in[6];
  float* out = (float*)d_out;

  // ws: fc1wT 512KB | w2pT 4MB | b2p 4KB | ... | hband 64MB at +8MB  (72MB total)
  bf16_t* fc1wT = (bf16_t*)d_ws;
  bf16_t* w2pT  = fc1wT + (size_t)HIDD * LATD;
  float*  b2p   = (float*)(w2pT + (size_t)JC * HIDD);
  bf16_t* hband = (bf16_t*)((char*)d_ws + (8u << 20));

  prep_fc1<<<(HIDD * LATD) / 256, 256, 0, stream>>>(fc1w, fc1wT);
  prep_fc2<<<(JC * HIDD) / 256, 256, 0, stream>>>(x, fc2w, fc2b, dil, shp, w2pT, b2p);

  for (int band = 0; band < NB / BAND; ++band) {
    h_kernel<<<BAND / HBLK, 512, 0, stream>>>(x, fc1b, fc1wT, hband, band);
    wag_main<<<dim3(BAND / WBM, JC / WBN), 512, 0, stream>>>(x, hband, w2pT, b2p, out, band);
  }
}